// Round 2
// baseline (335.202 us; speedup 1.0000x reference)
//
#include <hip/hip_runtime.h>

typedef unsigned short ushort_t;
typedef __attribute__((ext_vector_type(8))) short bf16x8;     // 8 bf16 (4 VGPRs)
typedef __attribute__((ext_vector_type(4))) float f32x4;
typedef __attribute__((ext_vector_type(4))) unsigned short us4;

#define DM 2048
#define RK 64
#define MTOT 16384
#define MB 16            // rows per block in main kernel

__device__ __forceinline__ float b2f(ushort_t v) {
    union { unsigned u; float f; } x; x.u = ((unsigned)v) << 16; return x.f;
}
__device__ __forceinline__ ushort_t f2b(float f) {
    union { float f; unsigned u; } x; x.f = f;
    unsigned r = x.u + 0x7fff + ((x.u >> 16) & 1);   // RNE
    return (ushort_t)(r >> 16);
}

// ---- prep: butterfly operator Bf[256][256] = kron(A0..A7), MSB-first ----
__global__ void k_bf(const float* __restrict__ Af, float* __restrict__ Bf) {
    __shared__ float A[32];
    if (threadIdx.x < 32) A[threadIdx.x] = Af[threadIdx.x];
    __syncthreads();
    int i = blockIdx.x, j = threadIdx.x;
    float p = 1.0f;
#pragma unroll
    for (int l = 0; l < 8; ++l) {
        int bi = (i >> (7 - l)) & 1;
        int bj = (j >> (7 - l)) & 1;
        p *= A[l * 4 + bi * 2 + bj];
    }
    Bf[i * 256 + j] = p;
}

// ---- prep: T1[64][256] = W_b_state @ Bf ----
__global__ void k_t1(const float* __restrict__ Wbs, const float* __restrict__ Bf,
                     float* __restrict__ T1) {
    int r = blockIdx.x, j = threadIdx.x;
    float s = 0.f;
    for (int n = 0; n < 256; ++n) s += Wbs[r * 256 + n] * Bf[n * 256 + j];
    T1[r * 256 + j] = s;
}

// ---- prep: Mmid[64][64] = T1 @ W_c_rank ----
__global__ void k_mid(const float* __restrict__ T1, const float* __restrict__ Wcr,
                      float* __restrict__ Mmid) {
    int id = blockIdx.x * 256 + threadIdx.x;
    int r1 = id >> 6, r2 = id & 63;
    float s = 0.f;
    for (int n = 0; n < 256; ++n) s += T1[r1 * 256 + n] * Wcr[n * 64 + r2];
    Mmid[r1 * 64 + r2] = s;
}

// ---- prep: W_effT[n][k] = sum_r W_b_rank[k][r] * Mmid[r][n], bf16 out ----
__global__ void k_weff(const float* __restrict__ Wbr, const float* __restrict__ Mmid,
                       ushort_t* __restrict__ WeffT) {
    int id = blockIdx.x * 256 + threadIdx.x;   // 64*2048
    int n = id >> 11, k = id & 2047;
    float s = 0.f;
#pragma unroll 8
    for (int r = 0; r < 64; ++r) s += Wbr[k * 64 + r] * Mmid[r * 64 + n];
    WeffT[id] = f2b(s);
}

// ---- prep: W_cT[n][k] = W_c_model[k][n], bf16 out ----
__global__ void k_wct(const float* __restrict__ Wcm, ushort_t* __restrict__ WcT) {
    int id = blockIdx.x * 256 + threadIdx.x;   // 2048*64
    int n = id >> 6, k = id & 63;
    WcT[id] = f2b(Wcm[k * 2048 + n]);
}

// ---- main fused kernel: out = (u @ W_eff) @ W_c_model + D*u ----
// LDS: 32768 ushorts (64 KB). u-tile bf16 at element (r,c):
//   idx = r*2048 + ((c&~7) ^ ((r&7)<<3)) + (c&7)   (XOR swizzle, bank-friendly)
// t (16x64 bf16, stride 72) lives at ushort offset 31616 (clobbers row 15,
// logical cols >= 896 -> D-term falls back to global for those).
__global__ __launch_bounds__(256) void k_main(const float* __restrict__ u,
                                              const ushort_t* __restrict__ WeffT,
                                              const ushort_t* __restrict__ WcT,
                                              const float* __restrict__ Dvec,
                                              float* __restrict__ out) {
    __shared__ ushort_t lds[32768];

    const int tid = threadIdx.x;
    const int w = tid >> 6;
    const int lane = tid & 63;
    const int m16 = lane & 15;
    const int quad = lane >> 4;
    const size_t row0 = (size_t)blockIdx.x * MB;
    const float* ub = u + row0 * DM;

    // ---------- stage u tile (fp32 -> bf16 LDS), 32 iters x 1024 elts ----------
#pragma unroll 8
    for (int it = 0; it < 32; ++it) {
        int flat = it * 1024 + tid * 4;
        int r = flat >> 11, c = flat & 2047;
        float4 v = *(const float4*)(ub + flat);
        int phys = r * 2048 + (((c & ~7) ^ ((r & 7) << 3)) | (c & 7));
        us4 o;
        o.x = f2b(v.x); o.y = f2b(v.y); o.z = f2b(v.z); o.w = f2b(v.w);
        *(us4*)&lds[phys] = o;
    }
    __syncthreads();

    // ---------- phase 1: t[16][64] = u_tile @ W_eff (wave w -> cols w*16..+16) ----------
    f32x4 acc = {0.f, 0.f, 0.f, 0.f};
    const int n0 = w * 16;
    const int swzA = (m16 & 7) << 3;
    const ushort_t* Bp1 = WeffT + (size_t)(n0 + m16) * DM + quad * 8;
#pragma unroll 4
    for (int kk = 0; kk < 64; ++kk) {
        int c8 = kk * 32 + quad * 8;
        bf16x8 a = *(const bf16x8*)&lds[m16 * 2048 + (c8 ^ swzA)];
        bf16x8 b = *(const bf16x8*)(Bp1 + kk * 32);
        acc = __builtin_amdgcn_mfma_f32_16x16x32_bf16(a, b, acc, 0, 0, 0);
    }
    __syncthreads();   // all phase-1 LDS reads done before t clobbers the tail

    // C layout: col = lane&15, row = quad*4+i
#pragma unroll
    for (int i = 0; i < 4; ++i)
        lds[31616 + (quad * 4 + i) * 72 + n0 + m16] = f2b(acc[i]);
    __syncthreads();

    // ---------- phase 2: out = t @ W_c_model + D*u ----------
    bf16x8 ta0 = *(const bf16x8*)&lds[31616 + m16 * 72 + quad * 8];
    bf16x8 ta1 = *(const bf16x8*)&lds[31616 + m16 * 72 + 32 + quad * 8];

    for (int nt = 0; nt < 32; ++nt) {
        const int n0c = w * 512 + nt * 16;
        const int colc = n0c + m16;
        const ushort_t* Bp = WcT + (size_t)colc * RK + quad * 8;
        bf16x8 b0 = *(const bf16x8*)(Bp);
        bf16x8 b1 = *(const bf16x8*)(Bp + 32);
        f32x4 o = {0.f, 0.f, 0.f, 0.f};
        o = __builtin_amdgcn_mfma_f32_16x16x32_bf16(ta0, b0, o, 0, 0, 0);
        o = __builtin_amdgcn_mfma_f32_16x16x32_bf16(ta1, b1, o, 0, 0, 0);
        const float dv = Dvec[colc];
        const int c8 = n0c + (m16 & 8);
        const int lowc = m16 & 7;
#pragma unroll
        for (int i = 0; i < 4; ++i) {
            int r = quad * 4 + i;
            int phys = r * 2048 + ((c8 ^ ((r & 7) << 3)) | lowc);
            float uv = b2f(lds[phys]);
            if (r == 15 && colc >= 896)        // t clobbered this region
                uv = ub[15 * 2048 + colc];
            out[(row0 + r) * DM + colc] = o[i] + dv * uv;
        }
    }
}

extern "C" void kernel_launch(void* const* d_in, const int* in_sizes, int n_in,
                              void* d_out, int out_size, void* d_ws, size_t ws_size,
                              hipStream_t stream) {
    const float* u   = (const float*)d_in[0];
    const float* Af  = (const float*)d_in[1];
    const float* Wbr = (const float*)d_in[2];
    const float* Wbs = (const float*)d_in[3];
    const float* Wcr = (const float*)d_in[4];
    const float* Wcm = (const float*)d_in[5];
    const float* Dv  = (const float*)d_in[6];
    float* out = (float*)d_out;

    char* ws = (char*)d_ws;
    float*    Bf    = (float*)(ws + 0);          // 256*256*4 = 262144
    float*    T1    = (float*)(ws + 262144);     // 64*256*4  =  65536
    float*    Mmid  = (float*)(ws + 327680);     // 64*64*4   =  16384
    ushort_t* WeffT = (ushort_t*)(ws + 344064);  // 64*2048*2 = 262144
    ushort_t* WcT   = (ushort_t*)(ws + 606208);  // 2048*64*2 = 262144

    k_bf  <<<256, 256, 0, stream>>>(Af, Bf);
    k_t1  <<< 64, 256, 0, stream>>>(Wbs, Bf, T1);
    k_mid <<< 16, 256, 0, stream>>>(T1, Wcr, Mmid);
    k_weff<<<512, 256, 0, stream>>>(Wbr, Mmid, WeffT);
    k_wct <<<512, 256, 0, stream>>>(Wcm, WcT);
    k_main<<<MTOT / MB, 256, 0, stream>>>(u, WeffT, WcT, Dv, out);
}